// Round 1
// baseline (914.828 us; speedup 1.0000x reference)
//
#include <hip/hip_runtime.h>
#include <hip/hip_bf16.h>
#include <math.h>

// ---------------------------------------------------------------------------
// PositionalAttentionPooling — factored implementation
//   D=128 node dim, DL=78 linear part, MSL=50 positional part
//   pass1: tq/tp = tanh(feat@W^T+b)  [bf16, stride 80]
//          qWn/pWn = tq/tp @ Wn[:, :78]^T  [bf16]
//          segsum (d<78 via atomics w/ cnt multiplier; d>=78 via pos histogram)
//   coarse: segmean -> @Wc^T + bn  -> coarseWc [B,128]
//   pass2: att = sigmoid(eWn + posWn[pos] + coarseWc[b]) . Wa ; out += att*emb
//   final: out /= count
// ---------------------------------------------------------------------------

constexpr int D   = 128;
constexpr int DL  = 78;
constexpr int MSL = 50;
constexpr int RP  = 80;   // padded row stride for tq/tp

__device__ __forceinline__ float sigmoidf_(float x) {
    return 1.f / (1.f + __expf(-x));
}

__device__ __forceinline__ float waveSum(float v) {
    #pragma unroll
    for (int m = 1; m < 64; m <<= 1) v += __shfl_xor(v, m, 64);
    return v;
}

// --- small tables: tpos = tanh(pos_table) [50][50]; posWn = tpos @ Wn2^T [50][128]
__global__ void k_tables(const float* __restrict__ pos_table, const float* __restrict__ Wn,
                         float* __restrict__ tpos, float* __restrict__ posWn) {
    int t = threadIdx.x;
    for (int o = t; o < MSL * MSL; o += blockDim.x) tpos[o] = tanhf(pos_table[o]);
    __syncthreads();
    for (int o = t; o < MSL * D; o += blockDim.x) {
        int r = o / D, d = o % D;
        float acc = 0.f;
        for (int j = 0; j < MSL; ++j) acc += tpos[r * MSL + j] * Wn[d * D + DL + j];
        posWn[o] = acc;
    }
}

// --- exclusive scan of cnt -> prodOff (3 tiny kernels)
__global__ void k_scanA(const int* __restrict__ cnt, int P, int* __restrict__ chunkSum) {
    __shared__ int s[256];
    int p = blockIdx.x * 256 + threadIdx.x;
    s[threadIdx.x] = (p < P) ? cnt[p] : 0;
    __syncthreads();
    for (int st = 128; st > 0; st >>= 1) {
        if (threadIdx.x < st) s[threadIdx.x] += s[threadIdx.x + st];
        __syncthreads();
    }
    if (threadIdx.x == 0) chunkSum[blockIdx.x] = s[0];
}
__global__ void k_scanB(const int* __restrict__ chunkSum, int nC, int* __restrict__ chunkOff) {
    if (threadIdx.x == 0 && blockIdx.x == 0) {
        int run = 0;
        for (int i = 0; i < nC; ++i) { chunkOff[i] = run; run += chunkSum[i]; }
    }
}
__global__ void k_scanC(const int* __restrict__ cnt, int P, const int* __restrict__ chunkOff,
                        int* __restrict__ prodOff) {
    __shared__ int s[256];
    int t = threadIdx.x;
    int p = blockIdx.x * 256 + t;
    int v = (p < P) ? cnt[p] : 0;
    s[t] = v;
    __syncthreads();
    for (int st = 1; st < 256; st <<= 1) {
        int add = (t >= st) ? s[t - st] : 0;
        __syncthreads();
        s[t] += add;
        __syncthreads();
    }
    if (p < P) prodOff[p] = chunkOff[blockIdx.x] + s[t] - v;  // exclusive
}

// --- branch kernel: linear+tanh, @Wn1^T, segment accumulation (d<DL), counts/hist
template <bool IS_QUERY>
__global__ __launch_bounds__(256) void k_branch(
    const float* __restrict__ feat, const float* __restrict__ W, const float* __restrict__ bias,
    const float* __restrict__ Wn, const int* __restrict__ batch,
    const int* __restrict__ posid, const int* __restrict__ cnt, int Nrows,
    __hip_bfloat16* __restrict__ tE, __hip_bfloat16* __restrict__ eWn,
    float* __restrict__ segsum, float* __restrict__ segcnt, int* __restrict__ hist) {
    __shared__ float Wls[128 * 81];     // union: Wq[78][129] then Wn1[128][81]
    __shared__ float featL[16 * 132];
    __shared__ float linL[16 * RP];
    int t = threadIdx.x;
    int r0 = blockIdx.x * 16;

    for (int o = t; o < DL * D; o += 256) { int d = o >> 7, k = o & 127; Wls[d * 129 + k] = W[o]; }
    for (int o = t; o < 16 * D; o += 256) {
        int q = o >> 7, k = o & 127;
        int r = r0 + q;
        featL[q * 132 + k] = (r < Nrows) ? feat[(size_t)r * D + k] : 0.f;
    }
    __syncthreads();

    // phase1: lin = tanh(feat @ W^T + b)
    for (int o = t; o < 16 * RP; o += 256) {
        int q = o / RP, d = o - q * RP;
        if (d < DL) {
            float acc = bias[d];
            const float* fr = &featL[q * 132];
            const float* wr = &Wls[d * 129];
            #pragma unroll 8
            for (int k = 0; k < D; ++k) acc += fr[k] * wr[k];
            float tv = tanhf(acc);
            linL[q * RP + d] = tv;
            int r = r0 + q;
            if (r < Nrows) tE[(size_t)r * RP + d] = __float2bfloat16(tv);
        }
    }
    __syncthreads();

    // load Wn1 [128][78] (overwrite Wls)
    for (int o = t; o < D * DL; o += 256) { int d = o / DL, j = o - d * DL; Wls[d * 81 + j] = Wn[d * D + j]; }
    __syncthreads();

    // phase2: eWn = lin @ Wn1^T
    for (int o = t; o < 16 * D; o += 256) {
        int q = o >> 7, d = o & 127;
        float acc = 0.f;
        const float* lr = &linL[q * RP];
        const float* wr = &Wls[d * 81];
        #pragma unroll 6
        for (int j = 0; j < DL; ++j) acc += lr[j] * wr[j];
        int r = r0 + q;
        if (r < Nrows) eWn[(size_t)r * D + d] = __float2bfloat16(acc);
    }

    // phase3: segment sums for d<DL (+ counts, query hist)
    for (int o = t; o < 16 * RP; o += 256) {
        int q = o / RP, d = o - q * RP;
        int r = r0 + q;
        if (d < DL && r < Nrows) {
            float m = IS_QUERY ? 1.f : (float)cnt[r];
            atomicAdd(&segsum[(size_t)batch[r] * D + d], m * linL[q * RP + d]);
        }
    }
    if (t < 16) {
        int r = r0 + t;
        if (r < Nrows) {
            int b = batch[r];
            if (IS_QUERY) {
                atomicAdd(&segcnt[b], 1.f);
                atomicAdd(&hist[b * MSL + posid[r]], 1);
            } else {
                atomicAdd(&segcnt[b], (float)cnt[r]);
            }
        }
    }
}

// --- histogram of product-node positions
__global__ void k_hist_prod(const int* __restrict__ ppos, const int* __restrict__ pbatch,
                            const int* __restrict__ prodOff, const int* __restrict__ cnt,
                            int P, int* __restrict__ hist) {
    int p = blockIdx.x * 256 + threadIdx.x;
    if (p >= P) return;
    int b = pbatch[p], off = prodOff[p], c = cnt[p];
    for (int j = 0; j < c; ++j) atomicAdd(&hist[b * MSL + ppos[off + j]], 1);
}

// --- positional part of segsum: segsum[b][78+k] = sum_r hist[b][r]*tpos[r][k]
__global__ void k_possum(const int* __restrict__ hist, const float* __restrict__ tpos,
                         int B, float* __restrict__ segsum) {
    int t = threadIdx.x;
    int bb = t / MSL, k = t - bb * MSL;
    if (bb >= 5) return;
    int b = blockIdx.x * 5 + bb;
    if (b >= B) return;
    float acc = 0.f;
    for (int r = 0; r < MSL; ++r) acc += (float)hist[b * MSL + r] * tpos[r * MSL + k];
    segsum[(size_t)b * D + DL + k] = acc;
}

// --- coarse = segsum/cnt ; coarseWc = coarse @ Wc^T + bn
__global__ __launch_bounds__(256) void k_coarse(
    const float* __restrict__ segsum, const float* __restrict__ segcnt,
    const float* __restrict__ Wc, const float* __restrict__ bn, int B,
    float* __restrict__ coarseWc) {
    __shared__ __hip_bfloat16 WcL[128 * 130];
    __shared__ float cL[16 * 128];
    int t = threadIdx.x;
    int b0 = blockIdx.x * 16;
    for (int o = t; o < D * D; o += 256) {
        int d = o >> 7, k = o & 127;
        WcL[d * 130 + k] = __float2bfloat16(Wc[o]);
    }
    for (int o = t; o < 16 * D; o += 256) {
        int bb = o >> 7, d = o & 127;
        int b = b0 + bb;
        cL[o] = (b < B) ? segsum[(size_t)b * D + d] / fmaxf(segcnt[b], 1.f) : 0.f;
    }
    __syncthreads();
    for (int o = t; o < 16 * D; o += 256) {
        int bb = o >> 7, d = o & 127;
        int b = b0 + bb;
        if (b >= B) continue;
        float acc = bn[d];
        const float* cr = &cL[bb * 128];
        const __hip_bfloat16* wr = &WcL[d * 130];
        #pragma unroll 8
        for (int j = 0; j < D; ++j) acc += cr[j] * __bfloat162float(wr[j]);
        coarseWc[(size_t)b * D + d] = acc;
    }
}

// --- pass2 products: wave per product
__global__ __launch_bounds__(256) void k_att_prod(
    const __hip_bfloat16* __restrict__ pWn, const __hip_bfloat16* __restrict__ tp,
    const float* __restrict__ coarseWc, const float* __restrict__ posWn,
    const float* __restrict__ tpos, const float* __restrict__ Wa,
    const int* __restrict__ pbatch, const int* __restrict__ prodOff,
    const int* __restrict__ cnt, const int* __restrict__ ppos,
    int P, float* __restrict__ out) {
    int p = blockIdx.x * 4 + (threadIdx.x >> 6);
    int l = threadIdx.x & 63;
    if (p >= P) return;
    int b = pbatch[p], off = prodOff[p], c = cnt[p];
    float base0 = __bfloat162float(pWn[(size_t)p * D + l])      + coarseWc[(size_t)b * D + l];
    float base1 = __bfloat162float(pWn[(size_t)p * D + 64 + l]) + coarseWc[(size_t)b * D + 64 + l];
    float wa0 = Wa[l], wa1 = Wa[64 + l];
    float attsum = 0.f, posacc = 0.f;
    for (int j = 0; j < c; ++j) {
        int pos = ppos[off + j];
        float z0 = base0 + posWn[pos * D + l];
        float z1 = base1 + posWn[pos * D + 64 + l];
        float part = sigmoidf_(z0) * wa0 + sigmoidf_(z1) * wa1;
        float att = waveSum(part);
        attsum += att;
        if (l >= 14) posacc += att * tpos[pos * MSL + (l - 14)];
    }
    float t0 = __bfloat162float(tp[(size_t)p * RP + l]);
    atomicAdd(&out[(size_t)b * D + l], attsum * t0);
    if (l < 14) {
        float t1 = __bfloat162float(tp[(size_t)p * RP + 64 + l]);
        atomicAdd(&out[(size_t)b * D + 64 + l], attsum * t1);
    } else {
        atomicAdd(&out[(size_t)b * D + 64 + l], posacc);
    }
}

// --- pass2 queries: wave per query
__global__ __launch_bounds__(256) void k_att_query(
    const __hip_bfloat16* __restrict__ qWn, const __hip_bfloat16* __restrict__ tq,
    const float* __restrict__ coarseWc, const float* __restrict__ posWn,
    const float* __restrict__ tpos, const float* __restrict__ Wa,
    const int* __restrict__ qbatch, const int* __restrict__ qpos,
    int NQ, float* __restrict__ out) {
    int q = blockIdx.x * 4 + (threadIdx.x >> 6);
    int l = threadIdx.x & 63;
    if (q >= NQ) return;
    int b = qbatch[q], pos = qpos[q];
    float z0 = __bfloat162float(qWn[(size_t)q * D + l])      + coarseWc[(size_t)b * D + l]      + posWn[pos * D + l];
    float z1 = __bfloat162float(qWn[(size_t)q * D + 64 + l]) + coarseWc[(size_t)b * D + 64 + l] + posWn[pos * D + 64 + l];
    float part = sigmoidf_(z0) * Wa[l] + sigmoidf_(z1) * Wa[64 + l];
    float att = waveSum(part);
    float e0 = __bfloat162float(tq[(size_t)q * RP + l]);
    atomicAdd(&out[(size_t)b * D + l], att * e0);
    float e1 = (l < 14) ? __bfloat162float(tq[(size_t)q * RP + 64 + l]) : tpos[pos * MSL + (l - 14)];
    atomicAdd(&out[(size_t)b * D + 64 + l], att * e1);
}

// --- finalize: divide by counts
__global__ void k_final(float* __restrict__ out, const float* __restrict__ segcnt, int B) {
    int i = blockIdx.x * 256 + threadIdx.x;
    if (i < B * D) out[i] = out[i] / fmaxf(segcnt[i >> 7], 1.f);
}

extern "C" void kernel_launch(void* const* d_in, const int* in_sizes, int n_in,
                              void* d_out, int out_size, void* d_ws, size_t ws_size,
                              hipStream_t stream) {
    const float* query_feat   = (const float*)d_in[0];
    const float* product_feat = (const float*)d_in[1];
    const float* Wq = (const float*)d_in[2];
    const float* bq = (const float*)d_in[3];
    const float* Wp = (const float*)d_in[4];
    const float* bp = (const float*)d_in[5];
    const float* pos_table = (const float*)d_in[6];
    const float* Wn = (const float*)d_in[7];
    const float* bn = (const float*)d_in[8];
    const float* Wc = (const float*)d_in[9];
    const float* Wa = (const float*)d_in[10];
    const int* qpos   = (const int*)d_in[11];
    const int* ppos   = (const int*)d_in[12];
    const int* qbatch = (const int*)d_in[13];
    const int* pbatch = (const int*)d_in[14];
    const int* cnt    = (const int*)d_in[15];

    int NQ = in_sizes[11];
    int P  = in_sizes[15];
    int B  = out_size / D;
    float* out = (float*)d_out;

    // workspace layout (256B aligned chunks)
    char* w = (char*)d_ws;
    size_t off = 0;
    auto take = [&](size_t bytes) -> char* {
        char* p = w + off;
        off = (off + bytes + 255) & ~(size_t)255;
        return p;
    };
    float* segsum = (float*)take((size_t)B * D * 4);
    float* segcnt = (float*)take((size_t)B * 4);
    int*   hist   = (int*)  take((size_t)B * MSL * 4);
    size_t zeroBytes = off;  // segsum+segcnt+hist are contiguous from ws start
    float* coarseWc = (float*)take((size_t)B * D * 4);
    float* tpos  = (float*)take(MSL * MSL * 4);
    float* posWn = (float*)take(MSL * D * 4);
    int nC = (P + 255) / 256;
    int* chunkSum = (int*)take((size_t)nC * 4);
    int* chunkOff = (int*)take((size_t)nC * 4);
    int* prodOff  = (int*)take((size_t)P * 4);
    __hip_bfloat16* tq  = (__hip_bfloat16*)take((size_t)NQ * RP * 2);
    __hip_bfloat16* tp  = (__hip_bfloat16*)take((size_t)P * RP * 2);
    __hip_bfloat16* qWn = (__hip_bfloat16*)take((size_t)NQ * D * 2);
    __hip_bfloat16* pWn = (__hip_bfloat16*)take((size_t)P * D * 2);
    (void)ws_size; (void)n_in;

    hipMemsetAsync(segsum, 0, zeroBytes, stream);
    hipMemsetAsync(out, 0, (size_t)out_size * 4, stream);

    hipLaunchKernelGGL(k_tables, dim3(1), dim3(256), 0, stream, pos_table, Wn, tpos, posWn);
    hipLaunchKernelGGL(k_scanA, dim3(nC), dim3(256), 0, stream, cnt, P, chunkSum);
    hipLaunchKernelGGL(k_scanB, dim3(1), dim3(64), 0, stream, chunkSum, nC, chunkOff);
    hipLaunchKernelGGL(k_scanC, dim3(nC), dim3(256), 0, stream, cnt, P, chunkOff, prodOff);

    hipLaunchKernelGGL((k_branch<true>), dim3((NQ + 15) / 16), dim3(256), 0, stream,
                       query_feat, Wq, bq, Wn, qbatch, qpos, (const int*)nullptr, NQ,
                       tq, qWn, segsum, segcnt, hist);
    hipLaunchKernelGGL((k_branch<false>), dim3((P + 15) / 16), dim3(256), 0, stream,
                       product_feat, Wp, bp, Wn, pbatch, (const int*)nullptr, cnt, P,
                       tp, pWn, segsum, segcnt, hist);
    hipLaunchKernelGGL(k_hist_prod, dim3((P + 255) / 256), dim3(256), 0, stream,
                       ppos, pbatch, prodOff, cnt, P, hist);
    hipLaunchKernelGGL(k_possum, dim3((B + 4) / 5), dim3(256), 0, stream, hist, tpos, B, segsum);
    hipLaunchKernelGGL(k_coarse, dim3((B + 15) / 16), dim3(256), 0, stream,
                       segsum, segcnt, Wc, bn, B, coarseWc);

    hipLaunchKernelGGL(k_att_prod, dim3((P + 3) / 4), dim3(256), 0, stream,
                       pWn, tp, coarseWc, posWn, tpos, Wa, pbatch, prodOff, cnt, ppos, P, out);
    hipLaunchKernelGGL(k_att_query, dim3((NQ + 3) / 4), dim3(256), 0, stream,
                       qWn, tq, coarseWc, posWn, tpos, Wa, qbatch, qpos, NQ, out);
    hipLaunchKernelGGL(k_final, dim3((B * D + 255) / 256), dim3(256), 0, stream, out, segcnt, B);
}

// Round 2
// 465.760 us; speedup vs baseline: 1.9642x; 1.9642x over previous
//
#include <hip/hip_runtime.h>
#include <hip/hip_bf16.h>
#include <math.h>

// ---------------------------------------------------------------------------
// PositionalAttentionPooling — factored + MFMA branch GEMMs
//   D=128 node dim, DL=78 linear part, MSL=50 positional part
//   prep:  tpos=tanh(pos_table); posWn = tpos @ Wn2^T; bf16 weight tables
//   branch(MFMA): lin = tanh(feat@W^T+b) -> tE ; eWn = lin @ Wn1^T ;
//                 segsum atomics (d<78), segcnt, query pos hist
//   possum: segsum[b][78+k] from pos histogram  (tiny GEMM)
//   coarse: segmean -> @Wc^T + bn  -> coarseWc [B,128]
//   att:    att = sigmoid(eWn + posWn[pos] + coarseWc[b]) . Wa ; out += att*emb
//   final:  out /= count
// ---------------------------------------------------------------------------

constexpr int D   = 128;
constexpr int DL  = 78;
constexpr int MSL = 50;
constexpr int RP  = 80;   // padded row stride for tq/tp

typedef __attribute__((ext_vector_type(8))) short bfrag8;   // 8 bf16 (4 VGPR)
typedef __attribute__((ext_vector_type(4))) float facc4;    // 4 f32 acc
typedef __attribute__((ext_vector_type(4))) short short4v;  // 8B

__device__ __forceinline__ float sigmoidf_(float x) {
    return 1.f / (1.f + __expf(-x));
}

__device__ __forceinline__ float waveSum(float v) {
    #pragma unroll
    for (int m = 1; m < 64; m <<= 1) v += __shfl_xor(v, m, 64);
    return v;
}

// ---- swizzled LDS helpers (row stride 256B, XOR bits 4..6 by row&7) -------
__device__ __forceinline__ char* ldsAddr(__hip_bfloat16* base, int row, int byte_in_row) {
    return reinterpret_cast<char*>(base) + row * 256 + (byte_in_row ^ ((row & 7) << 4));
}
__device__ __forceinline__ bfrag8 ldsR16(const __hip_bfloat16* base, int row, int byte_in_row) {
    return *reinterpret_cast<const bfrag8*>(
        reinterpret_cast<const char*>(base) + row * 256 + (byte_in_row ^ ((row & 7) << 4)));
}
__device__ __forceinline__ short4v ldsR8(const __hip_bfloat16* base, int row, int byte_in_row) {
    return *reinterpret_cast<const short4v*>(
        reinterpret_cast<const char*>(base) + row * 256 + (byte_in_row ^ ((row & 7) << 4)));
}

// --- prep: small tables + bf16 weight tables
__global__ void k_prep(const float* __restrict__ pos_table, const float* __restrict__ Wn,
                       const float* __restrict__ Wq, const float* __restrict__ Wp,
                       float* __restrict__ tpos, float* __restrict__ posWn,
                       __hip_bfloat16* __restrict__ Wqbf, __hip_bfloat16* __restrict__ Wpbf,
                       __hip_bfloat16* __restrict__ Wnbf) {
    int t = threadIdx.x;
    for (int o = t; o < MSL * MSL; o += 256) tpos[o] = tanhf(pos_table[o]);
    __syncthreads();
    for (int o = t; o < MSL * D; o += 256) {
        int r = o >> 7, d = o & 127;
        float acc = 0.f;
        for (int j = 0; j < MSL; ++j) acc += tpos[r * MSL + j] * Wn[d * D + DL + j];
        posWn[o] = acc;
    }
    for (int o = t; o < 80 * 128; o += 256) {
        int n = o >> 7, k = o & 127;
        Wqbf[o] = (n < DL) ? __float2bfloat16(Wq[n * 128 + k]) : __float2bfloat16(0.f);
        Wpbf[o] = (n < DL) ? __float2bfloat16(Wp[n * 128 + k]) : __float2bfloat16(0.f);
    }
    for (int o = t; o < 128 * 128; o += 256) {
        int j = o & 127;
        Wnbf[o] = (j < DL) ? __float2bfloat16(Wn[o]) : __float2bfloat16(0.f);
    }
}

// --- exclusive scan of cnt -> prodOff (3 tiny kernels)
__global__ void k_scanA(const int* __restrict__ cnt, int P, int* __restrict__ chunkSum) {
    __shared__ int s[256];
    int p = blockIdx.x * 256 + threadIdx.x;
    s[threadIdx.x] = (p < P) ? cnt[p] : 0;
    __syncthreads();
    for (int st = 128; st > 0; st >>= 1) {
        if (threadIdx.x < st) s[threadIdx.x] += s[threadIdx.x + st];
        __syncthreads();
    }
    if (threadIdx.x == 0) chunkSum[blockIdx.x] = s[0];
}
__global__ void k_scanB(const int* __restrict__ chunkSum, int nC, int* __restrict__ chunkOff) {
    if (threadIdx.x == 0 && blockIdx.x == 0) {
        int run = 0;
        for (int i = 0; i < nC; ++i) { chunkOff[i] = run; run += chunkSum[i]; }
    }
}
__global__ void k_scanC(const int* __restrict__ cnt, int P, const int* __restrict__ chunkOff,
                        int* __restrict__ prodOff) {
    __shared__ int s[256];
    int t = threadIdx.x;
    int p = blockIdx.x * 256 + t;
    int v = (p < P) ? cnt[p] : 0;
    s[t] = v;
    __syncthreads();
    for (int st = 1; st < 256; st <<= 1) {
        int add = (t >= st) ? s[t - st] : 0;
        __syncthreads();
        s[t] += add;
        __syncthreads();
    }
    if (p < P) prodOff[p] = chunkOff[blockIdx.x] + s[t] - v;  // exclusive
}

// --- MFMA branch kernel: 64 rows per block, 4 waves
template <bool IS_QUERY>
__global__ __launch_bounds__(256) void k_branch(
    const float* __restrict__ feat, const __hip_bfloat16* __restrict__ Wbf,
    const float* __restrict__ bias, const __hip_bfloat16* __restrict__ Wnbf,
    const int* __restrict__ batch, const int* __restrict__ posid,
    const int* __restrict__ cnt, int Nrows,
    __hip_bfloat16* __restrict__ tE, __hip_bfloat16* __restrict__ eWn,
    float* __restrict__ segsum, float* __restrict__ segcnt, int* __restrict__ hist) {
    __shared__ __hip_bfloat16 featL[64 * 128];   // swizzled; reused as eWn staging
    __shared__ __hip_bfloat16 linL[64 * 128];    // swizzled; cols 0..95 valid (78+ zero)
    int t = threadIdx.x;
    int r0 = blockIdx.x * 64;

    // --- stage feat -> bf16 LDS (swizzled), zero K-pad bytes [160,192)
    {
        int r = t >> 2, c = t & 3;
        int gr = r0 + r;
        #pragma unroll
        for (int j = 0; j < 8; ++j) {
            int kf = c * 32 + j * 4;
            float4 v = make_float4(0.f, 0.f, 0.f, 0.f);
            if (gr < Nrows) v = *reinterpret_cast<const float4*>(&feat[(size_t)gr * 128 + kf]);
            __hip_bfloat16 tmp[4] = {__float2bfloat16(v.x), __float2bfloat16(v.y),
                                     __float2bfloat16(v.z), __float2bfloat16(v.w)};
            *reinterpret_cast<short4v*>(ldsAddr(featL, r, kf * 2)) = *reinterpret_cast<short4v*>(tmp);
        }
        if (c < 2) {
            short4v z = {0, 0, 0, 0};
            *reinterpret_cast<short4v*>(ldsAddr(linL, r, 160 + c * 16)) = z;
            *reinterpret_cast<short4v*>(ldsAddr(linL, r, 168 + c * 16)) = z;
        }
    }
    __syncthreads();

    int l = t & 63, w = t >> 6;
    int lr = l & 15, lq = l >> 4;
    int am = w * 16 + lr;       // A-fragment row (local)

    // --- phase1: C1[64,80] = featL @ Wbf^T   (B frags straight from global)
    bfrag8 a[4];
    #pragma unroll
    for (int kt = 0; kt < 4; ++kt) a[kt] = ldsR16(featL, am, kt * 64 + lq * 16);
    facc4 c1[5];
    #pragma unroll
    for (int nt = 0; nt < 5; ++nt) { facc4 z = {0.f, 0.f, 0.f, 0.f}; c1[nt] = z; }
    #pragma unroll
    for (int nt = 0; nt < 5; ++nt) {
        #pragma unroll
        for (int kt = 0; kt < 4; ++kt) {
            bfrag8 b = *reinterpret_cast<const bfrag8*>(&Wbf[(nt * 16 + lr) * 128 + kt * 32 + lq * 8]);
            c1[nt] = __builtin_amdgcn_mfma_f32_16x16x32_bf16(a[kt], b, c1[nt], 0, 0, 0);
        }
    }

    // --- epilogue1: tanh(+bias), write linL, segment atomics (d<78)
    int   bj[4];
    float mult[4];
    bool  valid[4];
    #pragma unroll
    for (int j = 0; j < 4; ++j) {
        int m = w * 16 + lq * 4 + j;
        int gr = r0 + m;
        valid[j] = gr < Nrows;
        bj[j]    = valid[j] ? batch[gr] : 0;
        mult[j]  = IS_QUERY ? 1.f : (valid[j] ? (float)cnt[gr] : 0.f);
    }
    #pragma unroll
    for (int nt = 0; nt < 5; ++nt) {
        int n = nt * 16 + lr;
        float bs = (n < DL) ? bias[n] : 0.f;
        #pragma unroll
        for (int j = 0; j < 4; ++j) {
            int m = w * 16 + lq * 4 + j;
            float tv = (n < DL) ? tanhf(c1[nt][j] + bs) : 0.f;
            *reinterpret_cast<__hip_bfloat16*>(ldsAddr(linL, m, 2 * n)) = __float2bfloat16(tv);
            if (n < DL && valid[j])
                atomicAdd(&segsum[(size_t)bj[j] * D + n], mult[j] * tv);
        }
    }
    __syncthreads();

    // --- copy linL -> tE (coalesced 8B)
    {
        int r = t >> 2, c = t & 3;
        int gr = r0 + r;
        #pragma unroll
        for (int j = 0; j < 5; ++j) {
            int byte = c * 40 + j * 8;
            short4v v = ldsR8(linL, r, byte);
            if (gr < Nrows)
                *reinterpret_cast<short4v*>(&tE[(size_t)gr * RP + c * 20 + j * 4]) = v;
        }
    }

    // --- phase2: C2[64,128] = linL[64,96] @ Wnbf^T
    bfrag8 a2[3];
    #pragma unroll
    for (int kt = 0; kt < 3; ++kt) a2[kt] = ldsR16(linL, am, kt * 64 + lq * 16);
    facc4 c2[8];
    #pragma unroll
    for (int nt = 0; nt < 8; ++nt) { facc4 z = {0.f, 0.f, 0.f, 0.f}; c2[nt] = z; }
    #pragma unroll
    for (int nt = 0; nt < 8; ++nt) {
        #pragma unroll
        for (int kt = 0; kt < 3; ++kt) {
            bfrag8 b = *reinterpret_cast<const bfrag8*>(&Wnbf[(nt * 16 + lr) * 128 + kt * 32 + lq * 8]);
            c2[nt] = __builtin_amdgcn_mfma_f32_16x16x32_bf16(a2[kt], b, c2[nt], 0, 0, 0);
        }
    }
    // stage eWn into featL (dead after phase1; all phase1 reads done pre-sync)
    #pragma unroll
    for (int nt = 0; nt < 8; ++nt) {
        int d2 = nt * 16 + lr;
        #pragma unroll
        for (int j = 0; j < 4; ++j) {
            int m = w * 16 + lq * 4 + j;
            *reinterpret_cast<__hip_bfloat16*>(ldsAddr(featL, m, 2 * d2)) =
                __float2bfloat16(c2[nt][j]);
        }
    }
    __syncthreads();

    // --- copy eWn staging -> global (coalesced 16B)
    {
        int r = t >> 2, c = t & 3;
        int gr = r0 + r;
        #pragma unroll
        for (int j = 0; j < 4; ++j) {
            int byte = c * 64 + j * 16;
            bfrag8 v = ldsR16(featL, r, byte);
            if (gr < Nrows)
                *reinterpret_cast<bfrag8*>(&eWn[(size_t)gr * 128 + c * 32 + j * 8]) = v;
        }
    }

    // --- per-row scalars: segcnt (+ query pos hist)
    if (t < 64) {
        int gr = r0 + t;
        if (gr < Nrows) {
            int b = batch[gr];
            if (IS_QUERY) {
                atomicAdd(&segcnt[b], 1.f);
                atomicAdd(&hist[b * MSL + posid[gr]], 1);
            } else {
                atomicAdd(&segcnt[b], (float)cnt[gr]);
            }
        }
    }
}

// --- histogram of product-node positions
__global__ void k_hist_prod(const int* __restrict__ ppos, const int* __restrict__ pbatch,
                            const int* __restrict__ prodOff, const int* __restrict__ cnt,
                            int P, int* __restrict__ hist) {
    int p = blockIdx.x * 256 + threadIdx.x;
    if (p >= P) return;
    int b = pbatch[p], off = prodOff[p], c = cnt[p];
    for (int j = 0; j < c; ++j) atomicAdd(&hist[b * MSL + ppos[off + j]], 1);
}

// --- positional part of segsum
__global__ void k_possum(const int* __restrict__ hist, const float* __restrict__ tpos,
                         int B, float* __restrict__ segsum) {
    int t = threadIdx.x;
    int bb = t / MSL, k = t - bb * MSL;
    if (bb >= 5) return;
    int b = blockIdx.x * 5 + bb;
    if (b >= B) return;
    float acc = 0.f;
    for (int r = 0; r < MSL; ++r) acc += (float)hist[b * MSL + r] * tpos[r * MSL + k];
    segsum[(size_t)b * D + DL + k] = acc;
}

// --- coarse = segsum/cnt ; coarseWc = coarse @ Wc^T + bn
__global__ __launch_bounds__(256) void k_coarse(
    const float* __restrict__ segsum, const float* __restrict__ segcnt,
    const float* __restrict__ Wc, const float* __restrict__ bn, int B,
    float* __restrict__ coarseWc) {
    __shared__ __hip_bfloat16 WcL[128 * 130];
    __shared__ float cL[16 * 128];
    int t = threadIdx.x;
    int b0 = blockIdx.x * 16;
    for (int o = t; o < D * D; o += 256) {
        int d = o >> 7, k = o & 127;
        WcL[d * 130 + k] = __float2bfloat16(Wc[o]);
    }
    for (int o = t; o < 16 * D; o += 256) {
        int bb = o >> 7, d = o & 127;
        int b = b0 + bb;
        cL[o] = (b < B) ? segsum[(size_t)b * D + d] / fmaxf(segcnt[b], 1.f) : 0.f;
    }
    __syncthreads();
    for (int o = t; o < 16 * D; o += 256) {
        int bb = o >> 7, d = o & 127;
        int b = b0 + bb;
        if (b >= B) continue;
        float acc = bn[d];
        const float* cr = &cL[bb * 128];
        const __hip_bfloat16* wr = &WcL[d * 130];
        #pragma unroll 8
        for (int j = 0; j < D; ++j) acc += cr[j] * __bfloat162float(wr[j]);
        coarseWc[(size_t)b * D + d] = acc;
    }
}

// --- pass2 products: wave per product
__global__ __launch_bounds__(256) void k_att_prod(
    const __hip_bfloat16* __restrict__ pWn, const __hip_bfloat16* __restrict__ tp,
    const float* __restrict__ coarseWc, const float* __restrict__ posWn,
    const float* __restrict__ tpos, const float* __restrict__ Wa,
    const int* __restrict__ pbatch, const int* __restrict__ prodOff,
    const int* __restrict__ cnt, const int* __restrict__ ppos,
    int P, float* __restrict__ out) {
    int p = blockIdx.x * 4 + (threadIdx.x >> 6);
    int l = threadIdx.x & 63;
    if (p >= P) return;
    int b = pbatch[p], off = prodOff[p], c = cnt[p];
    float base0 = __bfloat162float(pWn[(size_t)p * D + l])      + coarseWc[(size_t)b * D + l];
    float base1 = __bfloat162float(pWn[(size_t)p * D + 64 + l]) + coarseWc[(size_t)b * D + 64 + l];
    float wa0 = Wa[l], wa1 = Wa[64 + l];
    float attsum = 0.f, posacc = 0.f;
    for (int j = 0; j < c; ++j) {
        int pos = ppos[off + j];
        float z0 = base0 + posWn[pos * D + l];
        float z1 = base1 + posWn[pos * D + 64 + l];
        float part = sigmoidf_(z0) * wa0 + sigmoidf_(z1) * wa1;
        float att = waveSum(part);
        attsum += att;
        if (l >= 14) posacc += att * tpos[pos * MSL + (l - 14)];
    }
    float t0 = __bfloat162float(tp[(size_t)p * RP + l]);
    atomicAdd(&out[(size_t)b * D + l], attsum * t0);
    if (l < 14) {
        float t1 = __bfloat162float(tp[(size_t)p * RP + 64 + l]);
        atomicAdd(&out[(size_t)b * D + 64 + l], attsum * t1);
    } else {
        atomicAdd(&out[(size_t)b * D + 64 + l], posacc);
    }
}

// --- pass2 queries: wave per query
__global__ __launch_bounds__(256) void k_att_query(
    const __hip_bfloat16* __restrict__ qWn, const __hip_bfloat16* __restrict__ tq,
    const float* __restrict__ coarseWc, const float* __restrict__ posWn,
    const float* __restrict__ tpos, const float* __restrict__ Wa,
    const int* __restrict__ qbatch, const int* __restrict__ qpos,
    int NQ, float* __restrict__ out) {
    int q = blockIdx.x * 4 + (threadIdx.x >> 6);
    int l = threadIdx.x & 63;
    if (q >= NQ) return;
    int b = qbatch[q], pos = qpos[q];
    float z0 = __bfloat162float(qWn[(size_t)q * D + l])      + coarseWc[(size_t)b * D + l]      + posWn[pos * D + l];
    float z1 = __bfloat162float(qWn[(size_t)q * D + 64 + l]) + coarseWc[(size_t)b * D + 64 + l] + posWn[pos * D + 64 + l];
    float part = sigmoidf_(z0) * Wa[l] + sigmoidf_(z1) * Wa[64 + l];
    float att = waveSum(part);
    float e0 = __bfloat162float(tq[(size_t)q * RP + l]);
    atomicAdd(&out[(size_t)b * D + l], att * e0);
    float e1 = (l < 14) ? __bfloat162float(tq[(size_t)q * RP + 64 + l]) : tpos[pos * MSL + (l - 14)];
    atomicAdd(&out[(size_t)b * D + 64 + l], att * e1);
}

// --- finalize: divide by counts
__global__ void k_final(float* __restrict__ out, const float* __restrict__ segcnt, int B) {
    int i = blockIdx.x * 256 + threadIdx.x;
    if (i < B * D) out[i] = out[i] / fmaxf(segcnt[i >> 7], 1.f);
}

extern "C" void kernel_launch(void* const* d_in, const int* in_sizes, int n_in,
                              void* d_out, int out_size, void* d_ws, size_t ws_size,
                              hipStream_t stream) {
    const float* query_feat   = (const float*)d_in[0];
    const float* product_feat = (const float*)d_in[1];
    const float* Wq = (const float*)d_in[2];
    const float* bq = (const float*)d_in[3];
    const float* Wp = (const float*)d_in[4];
    const float* bp = (const float*)d_in[5];
    const float* pos_table = (const float*)d_in[6];
    const float* Wn = (const float*)d_in[7];
    const float* bn = (const float*)d_in[8];
    const float* Wc = (const float*)d_in[9];
    const float* Wa = (const float*)d_in[10];
    const int* qpos   = (const int*)d_in[11];
    const int* ppos   = (const int*)d_in[12];
    const int* qbatch = (const int*)d_in[13];
    const int* pbatch = (const int*)d_in[14];
    const int* cnt    = (const int*)d_in[15];

    int NQ = in_sizes[11];
    int P  = in_sizes[15];
    int B  = out_size / D;
    float* out = (float*)d_out;

    // workspace layout (256B aligned chunks)
    char* w = (char*)d_ws;
    size_t off = 0;
    auto take = [&](size_t bytes) -> char* {
        char* p = w + off;
        off = (off + bytes + 255) & ~(size_t)255;
        return p;
    };
    float* segsum = (float*)take((size_t)B * D * 4);
    float* segcnt = (float*)take((size_t)B * 4);
    int*   hist   = (int*)  take((size_t)B * MSL * 4);
    size_t zeroBytes = off;  // segsum+segcnt+hist contiguous from ws start
    float* coarseWc = (float*)take((size_t)B * D * 4);
    float* tpos  = (float*)take(MSL * MSL * 4);
    float* posWn = (float*)take(MSL * D * 4);
    __hip_bfloat16* Wqbf = (__hip_bfloat16*)take(80 * 128 * 2);
    __hip_bfloat16* Wpbf = (__hip_bfloat16*)take(80 * 128 * 2);
    __hip_bfloat16* Wnbf = (__hip_bfloat16*)take(128 * 128 * 2);
    int nC = (P + 255) / 256;
    int* chunkSum = (int*)take((size_t)nC * 4);
    int* chunkOff = (int*)take((size_t)nC * 4);
    int* prodOff  = (int*)take((size_t)P * 4);
    __hip_bfloat16* tq  = (__hip_bfloat16*)take((size_t)NQ * RP * 2);
    __hip_bfloat16* tp  = (__hip_bfloat16*)take((size_t)P * RP * 2);
    __hip_bfloat16* qWn = (__hip_bfloat16*)take((size_t)NQ * D * 2);
    __hip_bfloat16* pWn = (__hip_bfloat16*)take((size_t)P * D * 2);
    (void)ws_size; (void)n_in;

    hipMemsetAsync(segsum, 0, zeroBytes, stream);
    hipMemsetAsync(out, 0, (size_t)out_size * 4, stream);

    hipLaunchKernelGGL(k_prep, dim3(1), dim3(256), 0, stream,
                       pos_table, Wn, Wq, Wp, tpos, posWn, Wqbf, Wpbf, Wnbf);
    hipLaunchKernelGGL(k_scanA, dim3(nC), dim3(256), 0, stream, cnt, P, chunkSum);
    hipLaunchKernelGGL(k_scanB, dim3(1), dim3(64), 0, stream, chunkSum, nC, chunkOff);
    hipLaunchKernelGGL(k_scanC, dim3(nC), dim3(256), 0, stream, cnt, P, chunkOff, prodOff);

    hipLaunchKernelGGL((k_branch<true>), dim3((NQ + 63) / 64), dim3(256), 0, stream,
                       query_feat, Wqbf, bq, Wnbf, qbatch, qpos, (const int*)nullptr, NQ,
                       tq, qWn, segsum, segcnt, hist);
    hipLaunchKernelGGL((k_branch<false>), dim3((P + 63) / 64), dim3(256), 0, stream,
                       product_feat, Wpbf, bp, Wnbf, pbatch, (const int*)nullptr, cnt, P,
                       tp, pWn, segsum, segcnt, hist);
    hipLaunchKernelGGL(k_hist_prod, dim3((P + 255) / 256), dim3(256), 0, stream,
                       ppos, pbatch, prodOff, cnt, P, hist);
    hipLaunchKernelGGL(k_possum, dim3((B + 4) / 5), dim3(256), 0, stream, hist, tpos, B, segsum);
    hipLaunchKernelGGL(k_coarse, dim3((B + 15) / 16), dim3(256), 0, stream,
                       segsum, segcnt, Wc, bn, B, coarseWc);

    hipLaunchKernelGGL(k_att_prod, dim3((P + 3) / 4), dim3(256), 0, stream,
                       pWn, tp, coarseWc, posWn, tpos, Wa, pbatch, prodOff, cnt, ppos, P, out);
    hipLaunchKernelGGL(k_att_query, dim3((NQ + 3) / 4), dim3(256), 0, stream,
                       qWn, tq, coarseWc, posWn, tpos, Wa, qbatch, qpos, NQ, out);
    hipLaunchKernelGGL(k_final, dim3((B * D + 255) / 256), dim3(256), 0, stream, out, segcnt, B);
}

// Round 3
// 380.431 us; speedup vs baseline: 2.4047x; 1.2243x over previous
//
#include <hip/hip_runtime.h>
#include <hip/hip_bf16.h>
#include <math.h>

// ---------------------------------------------------------------------------
// PositionalAttentionPooling — factored + MFMA branch GEMMs
//   D=128 node dim, DL=78 linear part, MSL=50 positional part
//   tables:  tpos=tanh(pos_table); posWn = tpos @ Wn2^T  (parallel, LDS tpos)
//   convW:   bf16 weight tables (grid-strided)
//   branch(MFMA): lin = tanh(feat@W^T+b) -> tE ; eWn = lin @ Wn1^T ;
//                 segsum atomics (d<78), segcnt, query pos hist
//   possum:  segsum[b][78+k] from pos histogram  (tiny GEMM)
//   coarse:  segmean -> @Wc^T + bn  -> coarseWc [B,128]
//   att:     att = sigmoid(eWn + posWn[pos] + coarseWc[b]) . Wa ; out += att*emb
//   final:   out /= count
// ---------------------------------------------------------------------------

constexpr int D   = 128;
constexpr int DL  = 78;
constexpr int MSL = 50;
constexpr int RP  = 80;   // padded row stride for tq/tp

typedef __attribute__((ext_vector_type(8))) short bfrag8;   // 8 bf16 (4 VGPR)
typedef __attribute__((ext_vector_type(4))) float facc4;    // 4 f32 acc
typedef __attribute__((ext_vector_type(4))) short short4v;  // 8B

__device__ __forceinline__ float sigmoidf_(float x) {
    return 1.f / (1.f + __expf(-x));
}

__device__ __forceinline__ float waveSum(float v) {
    #pragma unroll
    for (int m = 1; m < 64; m <<= 1) v += __shfl_xor(v, m, 64);
    return v;
}

// ---- swizzled LDS helpers (row stride 256B, XOR bits 4..6 by row&7) -------
__device__ __forceinline__ char* ldsAddr(__hip_bfloat16* base, int row, int byte_in_row) {
    return reinterpret_cast<char*>(base) + row * 256 + (byte_in_row ^ ((row & 7) << 4));
}
__device__ __forceinline__ bfrag8 ldsR16(const __hip_bfloat16* base, int row, int byte_in_row) {
    return *reinterpret_cast<const bfrag8*>(
        reinterpret_cast<const char*>(base) + row * 256 + (byte_in_row ^ ((row & 7) << 4)));
}
__device__ __forceinline__ short4v ldsR8(const __hip_bfloat16* base, int row, int byte_in_row) {
    return *reinterpret_cast<const short4v*>(
        reinterpret_cast<const char*>(base) + row * 256 + (byte_in_row ^ ((row & 7) << 4)));
}

// --- tables: tpos = tanh(pos_table); posWn = tpos @ Wn2^T  (parallel)
__global__ __launch_bounds__(256) void k_tables2(
    const float* __restrict__ pos_table, const float* __restrict__ Wn,
    float* __restrict__ tpos, float* __restrict__ posWn) {
    __shared__ float tposL[MSL * MSL];
    int t = threadIdx.x;
    for (int o = t; o < MSL * MSL; o += 256) tposL[o] = tanhf(pos_table[o]);
    __syncthreads();
    if (blockIdx.x == 0)
        for (int o = t; o < MSL * MSL; o += 256) tpos[o] = tposL[o];
    for (int o = blockIdx.x * 256 + t; o < MSL * D; o += gridDim.x * 256) {
        int r = o >> 7, d = o & 127;
        float acc = 0.f;
        #pragma unroll 10
        for (int j = 0; j < MSL; ++j) acc += tposL[r * MSL + j] * Wn[d * D + DL + j];
        posWn[o] = acc;
    }
}

// --- convW: bf16 weight tables (Wq/Wp padded to 80 rows, Wn1 cols>=78 zeroed)
__global__ __launch_bounds__(256) void k_convW(
    const float* __restrict__ Wq, const float* __restrict__ Wp, const float* __restrict__ Wn,
    __hip_bfloat16* __restrict__ Wqbf, __hip_bfloat16* __restrict__ Wpbf,
    __hip_bfloat16* __restrict__ Wnbf) {
    int i = blockIdx.x * 256 + threadIdx.x;
    if (i < 80 * 128) {
        int n = i >> 7;
        Wqbf[i] = __float2bfloat16((n < DL) ? Wq[i] : 0.f);
        Wpbf[i] = __float2bfloat16((n < DL) ? Wp[i] : 0.f);
    } else if (i < 80 * 128 + 128 * 128) {
        int o = i - 80 * 128;
        int j = o & 127;
        Wnbf[o] = __float2bfloat16((j < DL) ? Wn[o] : 0.f);
    }
}

// --- exclusive scan of cnt -> prodOff
__global__ void k_scanA(const int* __restrict__ cnt, int P, int* __restrict__ chunkSum) {
    __shared__ int s[256];
    int p = blockIdx.x * 256 + threadIdx.x;
    s[threadIdx.x] = (p < P) ? cnt[p] : 0;
    __syncthreads();
    for (int st = 128; st > 0; st >>= 1) {
        if (threadIdx.x < st) s[threadIdx.x] += s[threadIdx.x + st];
        __syncthreads();
    }
    if (threadIdx.x == 0) chunkSum[blockIdx.x] = s[0];
}
// parallel single-block scan of chunk sums (Hillis-Steele, 1024-wide tiles)
__global__ __launch_bounds__(1024) void k_scanB(
    const int* __restrict__ chunkSum, int nC, int* __restrict__ chunkOff) {
    __shared__ int s[1024];
    int t = threadIdx.x;
    int carry = 0;
    for (int base = 0; base < nC; base += 1024) {
        int v = (base + t < nC) ? chunkSum[base + t] : 0;
        s[t] = v;
        __syncthreads();
        for (int st = 1; st < 1024; st <<= 1) {
            int add = (t >= st) ? s[t - st] : 0;
            __syncthreads();
            s[t] += add;
            __syncthreads();
        }
        if (base + t < nC) chunkOff[base + t] = carry + s[t] - v;  // exclusive
        carry += s[1023];
        __syncthreads();
    }
}
__global__ void k_scanC(const int* __restrict__ cnt, int P, const int* __restrict__ chunkOff,
                        int* __restrict__ prodOff) {
    __shared__ int s[256];
    int t = threadIdx.x;
    int p = blockIdx.x * 256 + t;
    int v = (p < P) ? cnt[p] : 0;
    s[t] = v;
    __syncthreads();
    for (int st = 1; st < 256; st <<= 1) {
        int add = (t >= st) ? s[t - st] : 0;
        __syncthreads();
        s[t] += add;
        __syncthreads();
    }
    if (p < P) prodOff[p] = chunkOff[blockIdx.x] + s[t] - v;  // exclusive
}

// --- MFMA branch kernel: 64 rows per block, 4 waves
template <bool IS_QUERY>
__global__ __launch_bounds__(256) void k_branch(
    const float* __restrict__ feat, const __hip_bfloat16* __restrict__ Wbf,
    const float* __restrict__ bias, const __hip_bfloat16* __restrict__ Wnbf,
    const int* __restrict__ batch, const int* __restrict__ posid,
    const int* __restrict__ cnt, int Nrows,
    __hip_bfloat16* __restrict__ tE, __hip_bfloat16* __restrict__ eWn,
    float* __restrict__ segsum, float* __restrict__ segcnt, int* __restrict__ hist) {
    __shared__ __hip_bfloat16 featL[64 * 128];   // swizzled; reused as eWn staging
    __shared__ __hip_bfloat16 linL[64 * 128];    // swizzled; cols 0..95 valid (78+ zero)
    int t = threadIdx.x;
    int r0 = blockIdx.x * 64;

    // --- stage feat -> bf16 LDS (swizzled), zero K-pad bytes [160,192)
    {
        int r = t >> 2, c = t & 3;
        int gr = r0 + r;
        #pragma unroll
        for (int j = 0; j < 8; ++j) {
            int kf = c * 32 + j * 4;
            float4 v = make_float4(0.f, 0.f, 0.f, 0.f);
            if (gr < Nrows) v = *reinterpret_cast<const float4*>(&feat[(size_t)gr * 128 + kf]);
            __hip_bfloat16 tmp[4] = {__float2bfloat16(v.x), __float2bfloat16(v.y),
                                     __float2bfloat16(v.z), __float2bfloat16(v.w)};
            *reinterpret_cast<short4v*>(ldsAddr(featL, r, kf * 2)) = *reinterpret_cast<short4v*>(tmp);
        }
        if (c < 2) {
            short4v z = {0, 0, 0, 0};
            *reinterpret_cast<short4v*>(ldsAddr(linL, r, 160 + c * 16)) = z;
            *reinterpret_cast<short4v*>(ldsAddr(linL, r, 168 + c * 16)) = z;
        }
    }
    __syncthreads();

    int l = t & 63, w = t >> 6;
    int lr = l & 15, lq = l >> 4;
    int am = w * 16 + lr;       // A-fragment row (local)

    // --- phase1: C1[64,80] = featL @ Wbf^T   (B frags straight from global)
    bfrag8 a[4];
    #pragma unroll
    for (int kt = 0; kt < 4; ++kt) a[kt] = ldsR16(featL, am, kt * 64 + lq * 16);
    facc4 c1[5];
    #pragma unroll
    for (int nt = 0; nt < 5; ++nt) { facc4 z = {0.f, 0.f, 0.f, 0.f}; c1[nt] = z; }
    #pragma unroll
    for (int nt = 0; nt < 5; ++nt) {
        #pragma unroll
        for (int kt = 0; kt < 4; ++kt) {
            bfrag8 b = *reinterpret_cast<const bfrag8*>(&Wbf[(nt * 16 + lr) * 128 + kt * 32 + lq * 8]);
            c1[nt] = __builtin_amdgcn_mfma_f32_16x16x32_bf16(a[kt], b, c1[nt], 0, 0, 0);
        }
    }

    // --- epilogue1: tanh(+bias), write linL, segment atomics (d<78)
    int   bj[4];
    float mult[4];
    bool  valid[4];
    #pragma unroll
    for (int j = 0; j < 4; ++j) {
        int m = w * 16 + lq * 4 + j;
        int gr = r0 + m;
        valid[j] = gr < Nrows;
        bj[j]    = valid[j] ? batch[gr] : 0;
        mult[j]  = IS_QUERY ? 1.f : (valid[j] ? (float)cnt[gr] : 0.f);
    }
    #pragma unroll
    for (int nt = 0; nt < 5; ++nt) {
        int n = nt * 16 + lr;
        float bs = (n < DL) ? bias[n] : 0.f;
        #pragma unroll
        for (int j = 0; j < 4; ++j) {
            int m = w * 16 + lq * 4 + j;
            float tv = (n < DL) ? tanhf(c1[nt][j] + bs) : 0.f;
            *reinterpret_cast<__hip_bfloat16*>(ldsAddr(linL, m, 2 * n)) = __float2bfloat16(tv);
            if (n < DL && valid[j])
                atomicAdd(&segsum[(size_t)bj[j] * D + n], mult[j] * tv);
        }
    }
    __syncthreads();

    // --- copy linL -> tE (coalesced 8B)
    {
        int r = t >> 2, c = t & 3;
        int gr = r0 + r;
        #pragma unroll
        for (int j = 0; j < 5; ++j) {
            int byte = c * 40 + j * 8;
            short4v v = ldsR8(linL, r, byte);
            if (gr < Nrows)
                *reinterpret_cast<short4v*>(&tE[(size_t)gr * RP + c * 20 + j * 4]) = v;
        }
    }

    // --- phase2: C2[64,128] = linL[64,96] @ Wnbf^T
    bfrag8 a2[3];
    #pragma unroll
    for (int kt = 0; kt < 3; ++kt) a2[kt] = ldsR16(linL, am, kt * 64 + lq * 16);
    facc4 c2[8];
    #pragma unroll
    for (int nt = 0; nt < 8; ++nt) { facc4 z = {0.f, 0.f, 0.f, 0.f}; c2[nt] = z; }
    #pragma unroll
    for (int nt = 0; nt < 8; ++nt) {
        #pragma unroll
        for (int kt = 0; kt < 3; ++kt) {
            bfrag8 b = *reinterpret_cast<const bfrag8*>(&Wnbf[(nt * 16 + lr) * 128 + kt * 32 + lq * 8]);
            c2[nt] = __builtin_amdgcn_mfma_f32_16x16x32_bf16(a2[kt], b, c2[nt], 0, 0, 0);
        }
    }
    // stage eWn into featL (dead after phase1; all phase1 reads done pre-sync)
    #pragma unroll
    for (int nt = 0; nt < 8; ++nt) {
        int d2 = nt * 16 + lr;
        #pragma unroll
        for (int j = 0; j < 4; ++j) {
            int m = w * 16 + lq * 4 + j;
            *reinterpret_cast<__hip_bfloat16*>(ldsAddr(featL, m, 2 * d2)) =
                __float2bfloat16(c2[nt][j]);
        }
    }
    __syncthreads();

    // --- copy eWn staging -> global (coalesced 16B)
    {
        int r = t >> 2, c = t & 3;
        int gr = r0 + r;
        #pragma unroll
        for (int j = 0; j < 4; ++j) {
            int byte = c * 64 + j * 16;
            bfrag8 v = ldsR16(featL, r, byte);
            if (gr < Nrows)
                *reinterpret_cast<bfrag8*>(&eWn[(size_t)gr * 128 + c * 32 + j * 8]) = v;
        }
    }

    // --- per-row scalars: segcnt (+ query pos hist)
    if (t < 64) {
        int gr = r0 + t;
        if (gr < Nrows) {
            int b = batch[gr];
            if (IS_QUERY) {
                atomicAdd(&segcnt[b], 1.f);
                atomicAdd(&hist[b * MSL + posid[gr]], 1);
            } else {
                atomicAdd(&segcnt[b], (float)cnt[gr]);
            }
        }
    }
}

// --- histogram of product-node positions
__global__ void k_hist_prod(const int* __restrict__ ppos, const int* __restrict__ pbatch,
                            const int* __restrict__ prodOff, const int* __restrict__ cnt,
                            int P, int* __restrict__ hist) {
    int p = blockIdx.x * 256 + threadIdx.x;
    if (p >= P) return;
    int b = pbatch[p], off = prodOff[p], c = cnt[p];
    for (int j = 0; j < c; ++j) atomicAdd(&hist[b * MSL + ppos[off + j]], 1);
}

// --- positional part of segsum
__global__ void k_possum(const int* __restrict__ hist, const float* __restrict__ tpos,
                         int B, float* __restrict__ segsum) {
    int t = threadIdx.x;
    int bb = t / MSL, k = t - bb * MSL;
    if (bb >= 5) return;
    int b = blockIdx.x * 5 + bb;
    if (b >= B) return;
    float acc = 0.f;
    for (int r = 0; r < MSL; ++r) acc += (float)hist[b * MSL + r] * tpos[r * MSL + k];
    segsum[(size_t)b * D + DL + k] = acc;
}

// --- coarse = segsum/cnt ; coarseWc = coarse @ Wc^T + bn
__global__ __launch_bounds__(256) void k_coarse(
    const float* __restrict__ segsum, const float* __restrict__ segcnt,
    const float* __restrict__ Wc, const float* __restrict__ bn, int B,
    float* __restrict__ coarseWc) {
    __shared__ __hip_bfloat16 WcL[128 * 130];
    __shared__ float cL[16 * 128];
    int t = threadIdx.x;
    int b0 = blockIdx.x * 16;
    for (int o = t; o < D * D; o += 256) {
        int d = o >> 7, k = o & 127;
        WcL[d * 130 + k] = __float2bfloat16(Wc[o]);
    }
    for (int o = t; o < 16 * D; o += 256) {
        int bb = o >> 7, d = o & 127;
        int b = b0 + bb;
        cL[o] = (b < B) ? segsum[(size_t)b * D + d] / fmaxf(segcnt[b], 1.f) : 0.f;
    }
    __syncthreads();
    for (int o = t; o < 16 * D; o += 256) {
        int bb = o >> 7, d = o & 127;
        int b = b0 + bb;
        if (b >= B) continue;
        float acc = bn[d];
        const float* cr = &cL[bb * 128];
        const __hip_bfloat16* wr = &WcL[d * 130];
        #pragma unroll 8
        for (int j = 0; j < D; ++j) acc += cr[j] * __bfloat162float(wr[j]);
        coarseWc[(size_t)b * D + d] = acc;
    }
}

// --- pass2 products: wave per product
__global__ __launch_bounds__(256) void k_att_prod(
    const __hip_bfloat16* __restrict__ pWn, const __hip_bfloat16* __restrict__ tp,
    const float* __restrict__ coarseWc, const float* __restrict__ posWn,
    const float* __restrict__ tpos, const float* __restrict__ Wa,
    const int* __restrict__ pbatch, const int* __restrict__ prodOff,
    const int* __restrict__ cnt, const int* __restrict__ ppos,
    int P, float* __restrict__ out) {
    int p = blockIdx.x * 4 + (threadIdx.x >> 6);
    int l = threadIdx.x & 63;
    if (p >= P) return;
    int b = pbatch[p], off = prodOff[p], c = cnt[p];
    float base0 = __bfloat162float(pWn[(size_t)p * D + l])      + coarseWc[(size_t)b * D + l];
    float base1 = __bfloat162float(pWn[(size_t)p * D + 64 + l]) + coarseWc[(size_t)b * D + 64 + l];
    float wa0 = Wa[l], wa1 = Wa[64 + l];
    float attsum = 0.f, posacc = 0.f;
    for (int j = 0; j < c; ++j) {
        int pos = ppos[off + j];
        float z0 = base0 + posWn[pos * D + l];
        float z1 = base1 + posWn[pos * D + 64 + l];
        float part = sigmoidf_(z0) * wa0 + sigmoidf_(z1) * wa1;
        float att = waveSum(part);
        attsum += att;
        if (l >= 14) posacc += att * tpos[pos * MSL + (l - 14)];
    }
    float t0 = __bfloat162float(tp[(size_t)p * RP + l]);
    atomicAdd(&out[(size_t)b * D + l], attsum * t0);
    if (l < 14) {
        float t1 = __bfloat162float(tp[(size_t)p * RP + 64 + l]);
        atomicAdd(&out[(size_t)b * D + 64 + l], attsum * t1);
    } else {
        atomicAdd(&out[(size_t)b * D + 64 + l], posacc);
    }
}

// --- pass2 queries: wave per query
__global__ __launch_bounds__(256) void k_att_query(
    const __hip_bfloat16* __restrict__ qWn, const __hip_bfloat16* __restrict__ tq,
    const float* __restrict__ coarseWc, const float* __restrict__ posWn,
    const float* __restrict__ tpos, const float* __restrict__ Wa,
    const int* __restrict__ qbatch, const int* __restrict__ qpos,
    int NQ, float* __restrict__ out) {
    int q = blockIdx.x * 4 + (threadIdx.x >> 6);
    int l = threadIdx.x & 63;
    if (q >= NQ) return;
    int b = qbatch[q], pos = qpos[q];
    float z0 = __bfloat162float(qWn[(size_t)q * D + l])      + coarseWc[(size_t)b * D + l]      + posWn[pos * D + l];
    float z1 = __bfloat162float(qWn[(size_t)q * D + 64 + l]) + coarseWc[(size_t)b * D + 64 + l] + posWn[pos * D + 64 + l];
    float part = sigmoidf_(z0) * Wa[l] + sigmoidf_(z1) * Wa[64 + l];
    float att = waveSum(part);
    float e0 = __bfloat162float(tq[(size_t)q * RP + l]);
    atomicAdd(&out[(size_t)b * D + l], att * e0);
    float e1 = (l < 14) ? __bfloat162float(tq[(size_t)q * RP + 64 + l]) : tpos[pos * MSL + (l - 14)];
    atomicAdd(&out[(size_t)b * D + 64 + l], att * e1);
}

// --- finalize: divide by counts
__global__ void k_final(float* __restrict__ out, const float* __restrict__ segcnt, int B) {
    int i = blockIdx.x * 256 + threadIdx.x;
    if (i < B * D) out[i] = out[i] / fmaxf(segcnt[i >> 7], 1.f);
}

extern "C" void kernel_launch(void* const* d_in, const int* in_sizes, int n_in,
                              void* d_out, int out_size, void* d_ws, size_t ws_size,
                              hipStream_t stream) {
    const float* query_feat   = (const float*)d_in[0];
    const float* product_feat = (const float*)d_in[1];
    const float* Wq = (const float*)d_in[2];
    const float* bq = (const float*)d_in[3];
    const float* Wp = (const float*)d_in[4];
    const float* bp = (const float*)d_in[5];
    const float* pos_table = (const float*)d_in[6];
    const float* Wn = (const float*)d_in[7];
    const float* bn = (const float*)d_in[8];
    const float* Wc = (const float*)d_in[9];
    const float* Wa = (const float*)d_in[10];
    const int* qpos   = (const int*)d_in[11];
    const int* ppos   = (const int*)d_in[12];
    const int* qbatch = (const int*)d_in[13];
    const int* pbatch = (const int*)d_in[14];
    const int* cnt    = (const int*)d_in[15];

    int NQ = in_sizes[11];
    int P  = in_sizes[15];
    int B  = out_size / D;
    float* out = (float*)d_out;

    // workspace layout (256B aligned chunks)
    char* w = (char*)d_ws;
    size_t off = 0;
    auto take = [&](size_t bytes) -> char* {
        char* p = w + off;
        off = (off + bytes + 255) & ~(size_t)255;
        return p;
    };
    float* segsum = (float*)take((size_t)B * D * 4);
    float* segcnt = (float*)take((size_t)B * 4);
    int*   hist   = (int*)  take((size_t)B * MSL * 4);
    size_t zeroBytes = off;  // segsum+segcnt+hist contiguous from ws start
    float* coarseWc = (float*)take((size_t)B * D * 4);
    float* tpos  = (float*)take(MSL * MSL * 4);
    float* posWn = (float*)take(MSL * D * 4);
    __hip_bfloat16* Wqbf = (__hip_bfloat16*)take(80 * 128 * 2);
    __hip_bfloat16* Wpbf = (__hip_bfloat16*)take(80 * 128 * 2);
    __hip_bfloat16* Wnbf = (__hip_bfloat16*)take(128 * 128 * 2);
    int nC = (P + 255) / 256;
    int* chunkSum = (int*)take((size_t)nC * 4);
    int* chunkOff = (int*)take((size_t)nC * 4);
    int* prodOff  = (int*)take((size_t)P * 4);
    __hip_bfloat16* tq  = (__hip_bfloat16*)take((size_t)NQ * RP * 2);
    __hip_bfloat16* tp  = (__hip_bfloat16*)take((size_t)P * RP * 2);
    __hip_bfloat16* qWn = (__hip_bfloat16*)take((size_t)NQ * D * 2);
    __hip_bfloat16* pWn = (__hip_bfloat16*)take((size_t)P * D * 2);
    (void)ws_size; (void)n_in;

    hipMemsetAsync(segsum, 0, zeroBytes, stream);
    hipMemsetAsync(out, 0, (size_t)out_size * 4, stream);

    hipLaunchKernelGGL(k_tables2, dim3(8), dim3(256), 0, stream, pos_table, Wn, tpos, posWn);
    hipLaunchKernelGGL(k_convW, dim3((80 * 128 + 128 * 128 + 255) / 256), dim3(256), 0, stream,
                       Wq, Wp, Wn, Wqbf, Wpbf, Wnbf);
    hipLaunchKernelGGL(k_scanA, dim3(nC), dim3(256), 0, stream, cnt, P, chunkSum);
    hipLaunchKernelGGL(k_scanB, dim3(1), dim3(1024), 0, stream, chunkSum, nC, chunkOff);
    hipLaunchKernelGGL(k_scanC, dim3(nC), dim3(256), 0, stream, cnt, P, chunkOff, prodOff);

    hipLaunchKernelGGL((k_branch<true>), dim3((NQ + 63) / 64), dim3(256), 0, stream,
                       query_feat, Wqbf, bq, Wnbf, qbatch, qpos, (const int*)nullptr, NQ,
                       tq, qWn, segsum, segcnt, hist);
    hipLaunchKernelGGL((k_branch<false>), dim3((P + 63) / 64), dim3(256), 0, stream,
                       product_feat, Wpbf, bp, Wnbf, pbatch, (const int*)nullptr, cnt, P,
                       tp, pWn, segsum, segcnt, hist);
    hipLaunchKernelGGL(k_hist_prod, dim3((P + 255) / 256), dim3(256), 0, stream,
                       ppos, pbatch, prodOff, cnt, P, hist);
    hipLaunchKernelGGL(k_possum, dim3((B + 4) / 5), dim3(256), 0, stream, hist, tpos, B, segsum);
    hipLaunchKernelGGL(k_coarse, dim3((B + 15) / 16), dim3(256), 0, stream,
                       segsum, segcnt, Wc, bn, B, coarseWc);

    hipLaunchKernelGGL(k_att_prod, dim3((P + 3) / 4), dim3(256), 0, stream,
                       pWn, tp, coarseWc, posWn, tpos, Wa, pbatch, prodOff, cnt, ppos, P, out);
    hipLaunchKernelGGL(k_att_query, dim3((NQ + 3) / 4), dim3(256), 0, stream,
                       qWn, tq, coarseWc, posWn, tpos, Wa, qbatch, qpos, NQ, out);
    hipLaunchKernelGGL(k_final, dim3((B * D + 255) / 256), dim3(256), 0, stream, out, segcnt, B);
}

// Round 4
// 311.106 us; speedup vs baseline: 2.9406x; 1.2228x over previous
//
#include <hip/hip_runtime.h>
#include <hip/hip_bf16.h>
#include <math.h>

// ---------------------------------------------------------------------------
// PositionalAttentionPooling — factored + MFMA branch GEMMs (one-barrier form)
//   D=128 node dim, DL=78 linear part, MSL=50 positional part
//   tables:  tpos=tanh(pos_table); posWn = tpos @ Wn2^T
//   convW:   bf16 weight tables
//   branch2(MFMA, merged q+p): A-frags direct from global f32; lin=tanh(feat@W^T+b)
//            -> linL(LDS) -> tE ; eWn = lin @ Wn1^T stored direct from acc;
//            segsum atomics (d<78), segcnt, pos hist (query + product nodes)
//   possum:  segsum[b][78+k] from pos histogram
//   coarse:  segmean -> @Wc^T + bn -> coarseWc [B,128]
//   att (merged): att = sigmoid(eWn + posWn[pos] + coarseWc[b]) . Wa ;
//            out += att*emb   (product path: 5-way ILP butterfly reductions)
//   final:   out /= count
// ---------------------------------------------------------------------------

constexpr int D   = 128;
constexpr int DL  = 78;
constexpr int MSL = 50;
constexpr int RP  = 80;   // padded row stride for tq/tp

typedef __attribute__((ext_vector_type(8))) short bfrag8;   // 8 bf16 (4 VGPR)
typedef __attribute__((ext_vector_type(4))) float facc4;    // 4 f32 acc
typedef __attribute__((ext_vector_type(4))) short short4v;  // 8B

__device__ __forceinline__ float sigmoidf_(float x) {
    return 1.f / (1.f + __expf(-x));
}

// ---- swizzled LDS helpers (row stride 256B, XOR bits 4..6 by row&7) -------
__device__ __forceinline__ char* ldsAddr(__hip_bfloat16* base, int row, int byte_in_row) {
    return reinterpret_cast<char*>(base) + row * 256 + (byte_in_row ^ ((row & 7) << 4));
}
__device__ __forceinline__ bfrag8 ldsR16(const __hip_bfloat16* base, int row, int byte_in_row) {
    return *reinterpret_cast<const bfrag8*>(
        reinterpret_cast<const char*>(base) + row * 256 + (byte_in_row ^ ((row & 7) << 4)));
}
__device__ __forceinline__ short4v ldsR8(const __hip_bfloat16* base, int row, int byte_in_row) {
    return *reinterpret_cast<const short4v*>(
        reinterpret_cast<const char*>(base) + row * 256 + (byte_in_row ^ ((row & 7) << 4)));
}

__device__ __forceinline__ bfrag8 cvt8(float4 a, float4 b) {
    __hip_bfloat16 t[8] = {__float2bfloat16(a.x), __float2bfloat16(a.y),
                           __float2bfloat16(a.z), __float2bfloat16(a.w),
                           __float2bfloat16(b.x), __float2bfloat16(b.y),
                           __float2bfloat16(b.z), __float2bfloat16(b.w)};
    return *reinterpret_cast<bfrag8*>(t);
}

// --- tables: tpos = tanh(pos_table); posWn = tpos @ Wn2^T  (parallel)
__global__ __launch_bounds__(256) void k_tables2(
    const float* __restrict__ pos_table, const float* __restrict__ Wn,
    float* __restrict__ tpos, float* __restrict__ posWn) {
    __shared__ float tposL[MSL * MSL];
    int t = threadIdx.x;
    for (int o = t; o < MSL * MSL; o += 256) tposL[o] = tanhf(pos_table[o]);
    __syncthreads();
    if (blockIdx.x == 0)
        for (int o = t; o < MSL * MSL; o += 256) tpos[o] = tposL[o];
    for (int o = blockIdx.x * 256 + t; o < MSL * D; o += gridDim.x * 256) {
        int r = o >> 7, d = o & 127;
        float acc = 0.f;
        #pragma unroll 10
        for (int j = 0; j < MSL; ++j) acc += tposL[r * MSL + j] * Wn[d * D + DL + j];
        posWn[o] = acc;
    }
}

// --- convW: bf16 weight tables (Wq/Wp padded to 80 rows, Wn1 cols>=78 zeroed)
__global__ __launch_bounds__(256) void k_convW(
    const float* __restrict__ Wq, const float* __restrict__ Wp, const float* __restrict__ Wn,
    __hip_bfloat16* __restrict__ Wqbf, __hip_bfloat16* __restrict__ Wpbf,
    __hip_bfloat16* __restrict__ Wnbf) {
    int i = blockIdx.x * 256 + threadIdx.x;
    if (i < 80 * 128) {
        int n = i >> 7;
        Wqbf[i] = __float2bfloat16((n < DL) ? Wq[i] : 0.f);
        Wpbf[i] = __float2bfloat16((n < DL) ? Wp[i] : 0.f);
    } else if (i < 80 * 128 + 128 * 128) {
        int o = i - 80 * 128;
        int j = o & 127;
        Wnbf[o] = __float2bfloat16((j < DL) ? Wn[o] : 0.f);
    }
}

// --- exclusive scan of cnt -> prodOff
__global__ void k_scanA(const int* __restrict__ cnt, int P, int* __restrict__ chunkSum) {
    __shared__ int s[256];
    int p = blockIdx.x * 256 + threadIdx.x;
    s[threadIdx.x] = (p < P) ? cnt[p] : 0;
    __syncthreads();
    for (int st = 128; st > 0; st >>= 1) {
        if (threadIdx.x < st) s[threadIdx.x] += s[threadIdx.x + st];
        __syncthreads();
    }
    if (threadIdx.x == 0) chunkSum[blockIdx.x] = s[0];
}
__global__ __launch_bounds__(1024) void k_scanB(
    const int* __restrict__ chunkSum, int nC, int* __restrict__ chunkOff) {
    __shared__ int s[1024];
    int t = threadIdx.x;
    int carry = 0;
    for (int base = 0; base < nC; base += 1024) {
        int v = (base + t < nC) ? chunkSum[base + t] : 0;
        s[t] = v;
        __syncthreads();
        for (int st = 1; st < 1024; st <<= 1) {
            int add = (t >= st) ? s[t - st] : 0;
            __syncthreads();
            s[t] += add;
            __syncthreads();
        }
        if (base + t < nC) chunkOff[base + t] = carry + s[t] - v;  // exclusive
        carry += s[1023];
        __syncthreads();
    }
}
__global__ void k_scanC(const int* __restrict__ cnt, int P, const int* __restrict__ chunkOff,
                        int* __restrict__ prodOff) {
    __shared__ int s[256];
    int t = threadIdx.x;
    int p = blockIdx.x * 256 + t;
    int v = (p < P) ? cnt[p] : 0;
    s[t] = v;
    __syncthreads();
    for (int st = 1; st < 256; st <<= 1) {
        int add = (t >= st) ? s[t - st] : 0;
        __syncthreads();
        s[t] += add;
        __syncthreads();
    }
    if (p < P) prodOff[p] = chunkOff[blockIdx.x] + s[t] - v;  // exclusive
}

// --- merged MFMA branch kernel: 64 rows/block, 4 waves, ONE barrier
__global__ __launch_bounds__(256, 3) void k_branch2(
    const float* __restrict__ qfeat, const float* __restrict__ pfeat,
    const __hip_bfloat16* __restrict__ Wqbf, const __hip_bfloat16* __restrict__ Wpbf,
    const float* __restrict__ bq, const float* __restrict__ bp,
    const __hip_bfloat16* __restrict__ Wnbf,
    const int* __restrict__ qbatch, const int* __restrict__ pbatch,
    const int* __restrict__ qpos, const int* __restrict__ ppos,
    const int* __restrict__ cnt, const int* __restrict__ prodOff,
    int NQ, int P, int qBlocks,
    __hip_bfloat16* __restrict__ tq, __hip_bfloat16* __restrict__ tp,
    __hip_bfloat16* __restrict__ qWn, __hip_bfloat16* __restrict__ pWn,
    float* __restrict__ segsum, float* __restrict__ segcnt, int* __restrict__ hist) {
    const bool isQ = (int)blockIdx.x < qBlocks;
    const int r0 = (isQ ? blockIdx.x : blockIdx.x - qBlocks) * 64;
    const float* feat = isQ ? qfeat : pfeat;
    const __hip_bfloat16* Wbf = isQ ? Wqbf : Wpbf;
    const float* bias = isQ ? bq : bp;
    const int* batch = isQ ? qbatch : pbatch;
    const int Nrows = isQ ? NQ : P;
    __hip_bfloat16* tE  = isQ ? tq : tp;
    __hip_bfloat16* eWn = isQ ? qWn : pWn;

    __shared__ __hip_bfloat16 linL[64 * 128];    // swizzled; cols 0..95 used
    int t = threadIdx.x;
    int l = t & 63, w = t >> 6;
    int lr = l & 15, lq = l >> 4;
    int am = w * 16 + lr;       // A-fragment row (local)

    // zero K-pad cols [80,96) (bytes [160,192)) of linL
    if (t < 64) {
        bfrag8 z = {0, 0, 0, 0, 0, 0, 0, 0};
        *reinterpret_cast<bfrag8*>(ldsAddr(linL, t, 160)) = z;
        *reinterpret_cast<bfrag8*>(ldsAddr(linL, t, 176)) = z;
    }

    // --- A-fragments straight from global f32 (row am, cols kt*32+lq*8..+7)
    int gra = r0 + am;
    const float* frow = &feat[(size_t)(gra < Nrows ? gra : Nrows - 1) * 128];
    bfrag8 a[4];
    #pragma unroll
    for (int kt = 0; kt < 4; ++kt) {
        float4 u = *reinterpret_cast<const float4*>(&frow[kt * 32 + lq * 8]);
        float4 v = *reinterpret_cast<const float4*>(&frow[kt * 32 + lq * 8 + 4]);
        a[kt] = cvt8(u, v);
    }

    // --- phase1: C1[64,80] = feat @ Wbf^T
    facc4 c1[5];
    #pragma unroll
    for (int nt = 0; nt < 5; ++nt) { facc4 z = {0.f, 0.f, 0.f, 0.f}; c1[nt] = z; }
    #pragma unroll
    for (int nt = 0; nt < 5; ++nt) {
        #pragma unroll
        for (int kt = 0; kt < 4; ++kt) {
            bfrag8 b = *reinterpret_cast<const bfrag8*>(&Wbf[(nt * 16 + lr) * 128 + kt * 32 + lq * 8]);
            c1[nt] = __builtin_amdgcn_mfma_f32_16x16x32_bf16(a[kt], b, c1[nt], 0, 0, 0);
        }
    }

    // --- epilogue1: tanh(+bias), write linL, segment atomics (d<78)
    int   bj[4];
    float mult[4];
    bool  valid[4];
    #pragma unroll
    for (int j = 0; j < 4; ++j) {
        int m = w * 16 + lq * 4 + j;
        int gr = r0 + m;
        valid[j] = gr < Nrows;
        bj[j]    = valid[j] ? batch[gr] : 0;
        mult[j]  = isQ ? 1.f : (valid[j] ? (float)cnt[gr] : 0.f);
    }
    #pragma unroll
    for (int nt = 0; nt < 5; ++nt) {
        int n = nt * 16 + lr;
        float bs = (n < DL) ? bias[n] : 0.f;
        #pragma unroll
        for (int j = 0; j < 4; ++j) {
            int m = w * 16 + lq * 4 + j;
            float tv = (n < DL) ? tanhf(c1[nt][j] + bs) : 0.f;
            *reinterpret_cast<__hip_bfloat16*>(ldsAddr(linL, m, 2 * n)) = __float2bfloat16(tv);
            if (n < DL && valid[j])
                atomicAdd(&segsum[(size_t)bj[j] * D + n], mult[j] * tv);
        }
    }
    __syncthreads();

    // --- copy linL -> tE (coalesced 8B)
    {
        int r = t >> 2, c = t & 3;
        int gr = r0 + r;
        #pragma unroll
        for (int j = 0; j < 5; ++j) {
            short4v v = ldsR8(linL, r, c * 40 + j * 8);
            if (gr < Nrows)
                *reinterpret_cast<short4v*>(&tE[(size_t)gr * RP + c * 20 + j * 4]) = v;
        }
    }

    // --- phase2: C2[64,128] = lin[64,96] @ Wnbf^T
    bfrag8 a2[3];
    #pragma unroll
    for (int kt = 0; kt < 3; ++kt) a2[kt] = ldsR16(linL, am, kt * 64 + lq * 16);
    facc4 c2[8];
    #pragma unroll
    for (int nt = 0; nt < 8; ++nt) { facc4 z = {0.f, 0.f, 0.f, 0.f}; c2[nt] = z; }
    #pragma unroll
    for (int nt = 0; nt < 8; ++nt) {
        #pragma unroll
        for (int kt = 0; kt < 3; ++kt) {
            bfrag8 b = *reinterpret_cast<const bfrag8*>(&Wnbf[(nt * 16 + lr) * 128 + kt * 32 + lq * 8]);
            c2[nt] = __builtin_amdgcn_mfma_f32_16x16x32_bf16(a2[kt], b, c2[nt], 0, 0, 0);
        }
    }
    // --- store eWn directly from accumulators (2B/lane, 16-lane 32B runs)
    #pragma unroll
    for (int j = 0; j < 4; ++j) {
        int m = w * 16 + lq * 4 + j;
        int gr = r0 + m;
        if (gr < Nrows) {
            #pragma unroll
            for (int nt = 0; nt < 8; ++nt)
                eWn[(size_t)gr * 128 + nt * 16 + lr] = __float2bfloat16(c2[nt][j]);
        }
    }

    // --- per-row scalars: segcnt + pos hist (query: 1 node; product: cnt nodes)
    if (t < 64) {
        int gr = r0 + t;
        if (gr < Nrows) {
            int b = batch[gr];
            if (isQ) {
                atomicAdd(&segcnt[b], 1.f);
                atomicAdd(&hist[b * MSL + qpos[gr]], 1);
            } else {
                int c = cnt[gr], off2 = prodOff[gr];
                atomicAdd(&segcnt[b], (float)c);
                for (int j = 0; j < c; ++j)
                    atomicAdd(&hist[b * MSL + ppos[off2 + j]], 1);
            }
        }
    }
}

// --- positional part of segsum
__global__ void k_possum(const int* __restrict__ hist, const float* __restrict__ tpos,
                         int B, float* __restrict__ segsum) {
    int t = threadIdx.x;
    int bb = t / MSL, k = t - bb * MSL;
    if (bb >= 5) return;
    int b = blockIdx.x * 5 + bb;
    if (b >= B) return;
    float acc = 0.f;
    for (int r = 0; r < MSL; ++r) acc += (float)hist[b * MSL + r] * tpos[r * MSL + k];
    segsum[(size_t)b * D + DL + k] = acc;
}

// --- coarse = segsum/cnt ; coarseWc = coarse @ Wc^T + bn
__global__ __launch_bounds__(256) void k_coarse(
    const float* __restrict__ segsum, const float* __restrict__ segcnt,
    const float* __restrict__ Wc, const float* __restrict__ bn, int B,
    float* __restrict__ coarseWc) {
    __shared__ __hip_bfloat16 WcL[128 * 130];
    __shared__ float cL[16 * 128];
    int t = threadIdx.x;
    int b0 = blockIdx.x * 16;
    for (int o = t; o < D * D; o += 256) {
        int d = o >> 7, k = o & 127;
        WcL[d * 130 + k] = __float2bfloat16(Wc[o]);
    }
    for (int o = t; o < 16 * D; o += 256) {
        int bb = o >> 7, d = o & 127;
        int b = b0 + bb;
        cL[o] = (b < B) ? segsum[(size_t)b * D + d] / fmaxf(segcnt[b], 1.f) : 0.f;
    }
    __syncthreads();
    for (int o = t; o < 16 * D; o += 256) {
        int bb = o >> 7, d = o & 127;
        int b = b0 + bb;
        if (b >= B) continue;
        float acc = bn[d];
        const float* cr = &cL[bb * 128];
        const __hip_bfloat16* wr = &WcL[d * 130];
        #pragma unroll 8
        for (int j = 0; j < D; ++j) acc += cr[j] * __bfloat162float(wr[j]);
        coarseWc[(size_t)b * D + d] = acc;
    }
}

// --- merged att kernel: product blocks then query blocks; wave per node-group
__global__ __launch_bounds__(256) void k_att(
    const __hip_bfloat16* __restrict__ pWn, const __hip_bfloat16* __restrict__ tp,
    const __hip_bfloat16* __restrict__ qWn, const __hip_bfloat16* __restrict__ tq,
    const float* __restrict__ coarseWc, const float* __restrict__ posWn,
    const float* __restrict__ tpos, const float* __restrict__ Wa,
    const int* __restrict__ pbatch, const int* __restrict__ qbatch,
    const int* __restrict__ prodOff, const int* __restrict__ cnt,
    const int* __restrict__ ppos, const int* __restrict__ qpos,
    int P, int NQ, int pBlocks, float* __restrict__ out) {
    int wv = threadIdx.x >> 6, l = threadIdx.x & 63;
    if ((int)blockIdx.x < pBlocks) {
        int p = blockIdx.x * 4 + wv;
        if (p >= P) return;
        int b = pbatch[p], off = prodOff[p], c = cnt[p];
        float base0 = __bfloat162float(pWn[(size_t)p * D + l])      + coarseWc[(size_t)b * D + l];
        float base1 = __bfloat162float(pWn[(size_t)p * D + 64 + l]) + coarseWc[(size_t)b * D + 64 + l];
        float wa0 = Wa[l], wa1 = Wa[64 + l];
        // 5-way ILP: compute all (masked) node parts, then interleaved butterflies
        float part[5];
        int   posr[5];
        #pragma unroll
        for (int j = 0; j < 5; ++j) {
            bool on = j < c;
            int pos = on ? ppos[off + j] : 0;
            posr[j] = pos;
            float z0 = base0 + posWn[pos * D + l];
            float z1 = base1 + posWn[pos * D + 64 + l];
            part[j] = on ? (sigmoidf_(z0) * wa0 + sigmoidf_(z1) * wa1) : 0.f;
        }
        #pragma unroll
        for (int m = 1; m < 64; m <<= 1) {
            #pragma unroll
            for (int j = 0; j < 5; ++j) part[j] += __shfl_xor(part[j], m, 64);
        }
        float attsum = part[0] + part[1] + part[2] + part[3] + part[4];
        float posacc = 0.f;
        if (l >= 14) {
            #pragma unroll
            for (int j = 0; j < 5; ++j)
                posacc += part[j] * tpos[posr[j] * MSL + (l - 14)];
        }
        float t0 = __bfloat162float(tp[(size_t)p * RP + l]);
        atomicAdd(&out[(size_t)b * D + l], attsum * t0);
        if (l < 14) {
            float t1 = __bfloat162float(tp[(size_t)p * RP + 64 + l]);
            atomicAdd(&out[(size_t)b * D + 64 + l], attsum * t1);
        } else {
            atomicAdd(&out[(size_t)b * D + 64 + l], posacc);
        }
    } else {
        int q = (blockIdx.x - pBlocks) * 4 + wv;
        if (q >= NQ) return;
        int b = qbatch[q], pos = qpos[q];
        float z0 = __bfloat162float(qWn[(size_t)q * D + l])      + coarseWc[(size_t)b * D + l]      + posWn[pos * D + l];
        float z1 = __bfloat162float(qWn[(size_t)q * D + 64 + l]) + coarseWc[(size_t)b * D + 64 + l] + posWn[pos * D + 64 + l];
        float part = sigmoidf_(z0) * Wa[l] + sigmoidf_(z1) * Wa[64 + l];
        #pragma unroll
        for (int m = 1; m < 64; m <<= 1) part += __shfl_xor(part, m, 64);
        float e0 = __bfloat162float(tq[(size_t)q * RP + l]);
        atomicAdd(&out[(size_t)b * D + l], part * e0);
        float e1 = (l < 14) ? __bfloat162float(tq[(size_t)q * RP + 64 + l]) : tpos[pos * MSL + (l - 14)];
        atomicAdd(&out[(size_t)b * D + 64 + l], part * e1);
    }
}

// --- finalize: divide by counts
__global__ void k_final(float* __restrict__ out, const float* __restrict__ segcnt, int B) {
    int i = blockIdx.x * 256 + threadIdx.x;
    if (i < B * D) out[i] = out[i] / fmaxf(segcnt[i >> 7], 1.f);
}

extern "C" void kernel_launch(void* const* d_in, const int* in_sizes, int n_in,
                              void* d_out, int out_size, void* d_ws, size_t ws_size,
                              hipStream_t stream) {
    const float* query_feat   = (const float*)d_in[0];
    const float* product_feat = (const float*)d_in[1];
    const float* Wq = (const float*)d_in[2];
    const float* bq = (const float*)d_in[3];
    const float* Wp = (const float*)d_in[4];
    const float* bp = (const float*)d_in[5];
    const float* pos_table = (const float*)d_in[6];
    const float* Wn = (const float*)d_in[7];
    const float* bn = (const float*)d_in[8];
    const float* Wc = (const float*)d_in[9];
    const float* Wa = (const float*)d_in[10];
    const int* qpos   = (const int*)d_in[11];
    const int* ppos   = (const int*)d_in[12];
    const int* qbatch = (const int*)d_in[13];
    const int* pbatch = (const int*)d_in[14];
    const int* cnt    = (const int*)d_in[15];

    int NQ = in_sizes[11];
    int P  = in_sizes[15];
    int B  = out_size / D;
    float* out = (float*)d_out;

    // workspace layout (256B aligned chunks)
    char* w = (char*)d_ws;
    size_t off = 0;
    auto take = [&](size_t bytes) -> char* {
        char* p = w + off;
        off = (off + bytes + 255) & ~(size_t)255;
        return p;
    };
    float* segsum = (float*)take((size_t)B * D * 4);
    float* segcnt = (float*)take((size_t)B * 4);
    int*   hist   = (int*)  take((size_t)B * MSL * 4);
    size_t zeroBytes = off;  // segsum+segcnt+hist contiguous from ws start
    float* coarseWc = (float*)take((size_t)B * D * 4);
    float* tpos  = (float*)take(MSL * MSL * 4);
    float* posWn = (float*)take(MSL * D * 4);
    __hip_bfloat16* Wqbf = (__hip_bfloat16*)take(80 * 128 * 2);
    __hip_bfloat16* Wpbf = (__hip_bfloat16*)take(80 * 128 * 2);
    __hip_bfloat16* Wnbf = (__hip_bfloat16*)take(128 * 128 * 2);
    int nC = (P + 255) / 256;
    int* chunkSum = (int*)take((size_t)nC * 4);
    int* chunkOff = (int*)take((size_t)nC * 4);
    int* prodOff  = (int*)take((size_t)P * 4);
    __hip_bfloat16* tq  = (__hip_bfloat16*)take((size_t)NQ * RP * 2);
    __hip_bfloat16* tp  = (__hip_bfloat16*)take((size_t)P * RP * 2);
    __hip_bfloat16* qWn = (__hip_bfloat16*)take((size_t)NQ * D * 2);
    __hip_bfloat16* pWn = (__hip_bfloat16*)take((size_t)P * D * 2);
    (void)ws_size; (void)n_in;

    hipMemsetAsync(segsum, 0, zeroBytes, stream);
    hipMemsetAsync(out, 0, (size_t)out_size * 4, stream);

    hipLaunchKernelGGL(k_tables2, dim3(8), dim3(256), 0, stream, pos_table, Wn, tpos, posWn);
    hipLaunchKernelGGL(k_convW, dim3((80 * 128 + 128 * 128 + 255) / 256), dim3(256), 0, stream,
                       Wq, Wp, Wn, Wqbf, Wpbf, Wnbf);
    hipLaunchKernelGGL(k_scanA, dim3(nC), dim3(256), 0, stream, cnt, P, chunkSum);
    hipLaunchKernelGGL(k_scanB, dim3(1), dim3(1024), 0, stream, chunkSum, nC, chunkOff);
    hipLaunchKernelGGL(k_scanC, dim3(nC), dim3(256), 0, stream, cnt, P, chunkOff, prodOff);

    int qBlocks = (NQ + 63) / 64, pBlocksBr = (P + 63) / 64;
    hipLaunchKernelGGL(k_branch2, dim3(qBlocks + pBlocksBr), dim3(256), 0, stream,
                       query_feat, product_feat, Wqbf, Wpbf, bq, bp, Wnbf,
                       qbatch, pbatch, qpos, ppos, cnt, prodOff, NQ, P, qBlocks,
                       tq, tp, qWn, pWn, segsum, segcnt, hist);

    hipLaunchKernelGGL(k_possum, dim3((B + 4) / 5), dim3(256), 0, stream, hist, tpos, B, segsum);
    hipLaunchKernelGGL(k_coarse, dim3((B + 15) / 16), dim3(256), 0, stream,
                       segsum, segcnt, Wc, bn, B, coarseWc);

    int pBlocksAtt = (P + 3) / 4, qBlocksAtt = (NQ + 3) / 4;
    hipLaunchKernelGGL(k_att, dim3(pBlocksAtt + qBlocksAtt), dim3(256), 0, stream,
                       pWn, tp, qWn, tq, coarseWc, posWn, tpos, Wa,
                       pbatch, qbatch, prodOff, cnt, ppos, qpos, P, NQ, pBlocksAtt, out);
    hipLaunchKernelGGL(k_final, dim3((B * D + 255) / 256), dim3(256), 0, stream, out, segcnt, B);
}